// Round 17
// baseline (275.035 us; speedup 1.0000x reference)
//
#include <hip/hip_runtime.h>

// H=256, N1=80000, N2=20000, E1=300000. Layer 0 of the reference is dead code.
// Pipeline: prep (zero cntpair+done + k-panel weights) -> gemm0 h=x@Wg+bg
// (bf16 MFMA; count_rank fused as tail blocks; scan block spin-waits on a
// device-scope done counter) -> edge_scatter -> gat_sage (2 dst/block) ->
// sage_fin -> gemm1 (TM=64, +bias+rownorm).
// R17: count_rank overlapped into gemm0's tail (one less launch + ~6us of
// serialization); gemm1 313 blocks instead of 157 (tail balance).
// NOTE: rocprof per-dispatch dur is inflated (serialized replay, cold cache);
// optimize against harness total only.

#define NS 80000
#define ND 20000

typedef float   float4v  __attribute__((ext_vector_type(4)));
typedef float   f32x4    __attribute__((ext_vector_type(4)));
typedef __bf16  bf16x8   __attribute__((ext_vector_type(8)));
typedef unsigned short ushort8v __attribute__((ext_vector_type(8)));
typedef unsigned short ushort2v __attribute__((ext_vector_type(2)));
typedef int     int4v    __attribute__((ext_vector_type(4)));

union frag_u { ushort8v u; bf16x8 b; };

__device__ __forceinline__ float us2f(unsigned short u) {
    union { unsigned int i; float f; } x; x.i = ((unsigned)u) << 16; return x.f;
}
__device__ __forceinline__ unsigned short f2us(float f) {
    union { __bf16 b; unsigned short u; } x; x.b = (__bf16)f; return x.u;
}
__device__ __forceinline__ float lrelu02(float x) { return x > 0.f ? x : 0.2f * x; }

// ---------------------------------------------------------------------------
// prep: blocks 0..255 -> Wgp (k-panel of Wg^T); 256..511 -> Wcp; 512.. ->
// zero cntpair+done. k-panel: Bp[((k>>3)*256 + col)*8 + (k&7)] = B^T[col][k]
// ---------------------------------------------------------------------------
__global__ __launch_bounds__(256) void prep_misc(
    const float* __restrict__ Wg, const float* __restrict__ Wl,
    const float* __restrict__ Wr, unsigned short* __restrict__ Wgp,
    unsigned short* __restrict__ Wcp, int* __restrict__ zerop, int nz4)
{
    const int b = blockIdx.x, t = threadIdx.x;
    if (b < 256) {
        const int n = b;
        const int k = t;
        Wgp[(((k >> 3) * 256) + n) * 8 + (k & 7)] = f2us(Wg[k * 256 + n]);
    } else if (b < 512) {
        const int n = b - 256;
        const int k0 = t;
        const int k1 = t + 256;
        Wcp[(((k0 >> 3) * 256) + n) * 8 + (k0 & 7)] = f2us(Wl[t * 256 + n]);
        Wcp[(((k1 >> 3) * 256) + n) * 8 + (k1 & 7)] = f2us(Wr[t * 256 + n]);
    } else {
        const int i = (b - 512) * 256 + t;
        if (i < nz4) ((int4v*)zerop)[i] = (int4v){0, 0, 0, 0};
    }
}

// ---------------------------------------------------------------------------
// bf16 MFMA GEMM: C[M,256] = A[M,KC] @ Bp (k-panel of B^T)
// TM=128: 512 thr = 8 waves (2 row x 4 col). TM=64: 256 thr = 4 waves (1x4).
// BK=32; A-only dbuf LDS; B frags DIRECT from global k-panel (coalesced);
// 1 barrier per K-step; A(kt+1) issued at top.
// EPI=0 (+SCAN/COUNT): write bf16 (h+bg) + fused al_s/al_d dots.
//   Block nblk = CSR scan (spins until all count blocks signal done).
//   Blocks > nblk = count_rank (class-aware counts + within-class rank).
// EPI=1: +bias, row-L2-normalize, f32 out (rows guarded).
// AF32: A is f32 (x), cvt during staging; M%TM==0 assumed for AF32 path.
// ---------------------------------------------------------------------------
template <int EPI, bool AF32, bool SCAN, int KC, int TM>
__global__ __launch_bounds__(512) void gemm_mfma(
    const void* __restrict__ Av, const unsigned short* __restrict__ Bp,
    int M,
    unsigned short* __restrict__ hb_out,
    const float* __restrict__ avs, const float* __restrict__ avd,
    float* __restrict__ al_s, float* __restrict__ al_d,
    const float* __restrict__ bias, float* __restrict__ outp,
    int nblk, int* __restrict__ cntpair, int* __restrict__ ptrp,
    const int* __restrict__ srcE, const int* __restrict__ dstE,
    int* __restrict__ rank, int E, int* __restrict__ done_ctr, int ncnt)
{
    __shared__ __align__(16) unsigned short Als[2][TM][40];
    __shared__ float red0[128];
    __shared__ float red1[128];
    __shared__ int   part[512];

    if (SCAN && (int)blockIdx.x > nblk) {
        // ---- count_rank tail blocks (overlap gemm's drain) ----
        const int i = ((int)blockIdx.x - nblk - 1) * 512 + (int)threadIdx.x;
        if (i < E) {
            const int d = dstE[i];
            const int cls = (srcE[i] < ND) ? 0 : 1;
            rank[i] = atomicAdd(&cntpair[2 * d + cls], 1);
        }
        __syncthreads();
        __threadfence();
        if (threadIdx.x == 0) atomicAdd(done_ctr, 1);
        return;
    }
    if (SCAN && (int)blockIdx.x == nblk) {
        // ---- CSR exclusive scan; wait for all count blocks first ----
        const int tid = threadIdx.x;
        if (tid == 0) {
            while (atomicAdd(done_ctr, 0) < ncnt) { __builtin_amdgcn_s_sleep(8); }
        }
        __syncthreads();
        const int chunk = (ND + 511) / 512;
        const int i0 = tid * chunk;
        const int i1 = min(i0 + chunk, ND);
        int s = 0;
        for (int i = i0; i < i1; ++i) s += cntpair[2*i] + cntpair[2*i+1];
        part[tid] = s;
        __syncthreads();
        for (int off = 1; off < 512; off <<= 1) {
            const int t = (tid >= off) ? part[tid - off] : 0;
            __syncthreads();
            part[tid] += t;
            __syncthreads();
        }
        int run = tid ? part[tid - 1] : 0;
        for (int i = i0; i < i1; ++i) { ptrp[i] = run; run += cntpair[2*i] + cntpair[2*i+1]; }
        if (tid == 511) ptrp[ND] = part[511];
        return;
    }

    const int tid  = threadIdx.x;
    const int lane = tid & 63;
    const int wid  = tid >> 6;
    const int wr   = (TM == 128) ? (wid >> 2) : 0;   // row half
    const int wc   = (TM == 128) ? (wid & 3) : wid;  // col quarter
    const int row0 = blockIdx.x * TM;
    const int lg   = lane >> 4;
    const int lm   = lane & 15;

    f32x4 acc[4][4] = {};
    constexpr int nk = KC >> 5;

    const int arow = tid >> 2;          // 0..TM-1
    const int akof = (tid & 3) * 8;

    float4v ar0, ar1;
    ushort8v ai;

    auto loadA = [&](int kt) {
        const int k0 = kt * 32 + akof;
        const int grow = row0 + arow;
        if constexpr (AF32) {
            const float* p = (const float*)Av + (size_t)grow * KC + k0;
            ar0 = *(const float4v*)p;
            ar1 = *(const float4v*)(p + 4);
        } else {
            if (grow < M)
                ai = *(const ushort8v*)((const unsigned short*)Av + (size_t)grow * KC + k0);
            else
                ai = (ushort8v){0,0,0,0,0,0,0,0};
        }
    };
    auto storeA = [&](int b) {
        if constexpr (AF32) {
            ushort8v t;
            t[0] = f2us(ar0[0]); t[1] = f2us(ar0[1]); t[2] = f2us(ar0[2]); t[3] = f2us(ar0[3]);
            t[4] = f2us(ar1[0]); t[5] = f2us(ar1[1]); t[6] = f2us(ar1[2]); t[7] = f2us(ar1[3]);
            *(ushort8v*)&Als[b][arow][akof] = t;
        } else {
            *(ushort8v*)&Als[b][arow][akof] = ai;
        }
    };

    loadA(0); storeA(0); __syncthreads();
    int cur = 0;

#pragma unroll
    for (int kt = 0; kt < nk; ++kt) {
        if (kt + 1 < nk) loadA(kt + 1);
        frag_u bf[4];
#pragma unroll
        for (int n = 0; n < 4; ++n)
            bf[n].u = *(const ushort8v*)(Bp +
                ((size_t)(kt*4 + lg) * 256 + wc*64 + n*16 + lm) * 8);
        frag_u af[4];
#pragma unroll
        for (int m = 0; m < 4; ++m)
            af[m].u = *(const ushort8v*)&Als[cur][wr*64 + m*16 + lm][lg*8];
#pragma unroll
        for (int m = 0; m < 4; ++m)
#pragma unroll
            for (int n = 0; n < 4; ++n)
                acc[m][n] = __builtin_amdgcn_mfma_f32_16x16x32_bf16(
                    af[m].b, bf[n].b, acc[m][n], 0, 0, 0);
        if (kt + 1 < nk) {
            storeA(cur ^ 1);
            __syncthreads();
            cur ^= 1;
        }
    }

    if constexpr (EPI == 0) {
        if (tid < TM) { red0[tid] = 0.f; red1[tid] = 0.f; }
        __syncthreads();
        float asv[4], adv[4], bgv[4];
#pragma unroll
        for (int n = 0; n < 4; ++n) {
            const int col = wc*64 + n*16 + lm;
            asv[n] = avs[col]; adv[n] = avd[col]; bgv[n] = bias[col];
        }
#pragma unroll
        for (int m = 0; m < 4; ++m) {
#pragma unroll
            for (int j = 0; j < 4; ++j) {
                const int lr = wr*64 + m*16 + lg*4 + j;
                float ps = 0.f, pd = 0.f;
#pragma unroll
                for (int n = 0; n < 4; ++n) {
                    const float v = acc[m][n][j];
                    ps += v * asv[n]; pd += v * adv[n];
                    hb_out[(size_t)(row0 + lr) * 256 + wc*64 + n*16 + lm] = f2us(v + bgv[n]);
                }
#pragma unroll
                for (int off = 1; off < 16; off <<= 1) {
                    ps += __shfl_xor(ps, off);
                    pd += __shfl_xor(pd, off);
                }
                if (lm == 0) { atomicAdd(&red0[lr], ps); atomicAdd(&red1[lr], pd); }
            }
        }
        __syncthreads();
        if (tid < TM) { al_s[row0 + tid] = red0[tid]; al_d[row0 + tid] = red1[tid]; }
    } else {
        if (tid < TM) red0[tid] = 0.f;
        __syncthreads();
        float bv[4];
#pragma unroll
        for (int n = 0; n < 4; ++n) bv[n] = bias[wc*64 + n*16 + lm];
#pragma unroll
        for (int m = 0; m < 4; ++m) {
#pragma unroll
            for (int j = 0; j < 4; ++j) {
                const int lr = wr*64 + m*16 + lg*4 + j;
                float ss = 0.f;
#pragma unroll
                for (int n = 0; n < 4; ++n) {
                    const float v = acc[m][n][j] + bv[n];
                    acc[m][n][j] = v;
                    ss += v * v;
                }
#pragma unroll
                for (int off = 1; off < 16; off <<= 1) ss += __shfl_xor(ss, off);
                if (lm == 0) atomicAdd(&red0[lr], ss);
            }
        }
        __syncthreads();
#pragma unroll
        for (int m = 0; m < 4; ++m) {
#pragma unroll
            for (int j = 0; j < 4; ++j) {
                const int lr = wr*64 + m*16 + lg*4 + j;
                const int grow = row0 + lr;
                if (grow < M) {
                    const float inv = 1.0f / fmaxf(sqrtf(red0[lr]), 1e-12f);
#pragma unroll
                    for (int n = 0; n < 4; ++n)
                        outp[(size_t)grow * 256 + wc*64 + n*16 + lm] = acc[m][n][j] * inv;
                }
            }
        }
    }
}

// ---------------------------------------------------------------------------
// scatter: atomic-free via rank; class-ordered (s<ND first within each row)
// ---------------------------------------------------------------------------
__global__ void edge_scatter(const int* __restrict__ src, const int* __restrict__ dst,
                             const int* __restrict__ ptrp, const int* __restrict__ rank,
                             const int* __restrict__ cntpair,
                             int* __restrict__ ssort, int E)
{
    const int i = blockIdx.x * 256 + threadIdx.x;
    if (i < E) {
        const int d = dst[i];
        const int s = src[i];
        const int base = ptrp[d];
        const int pos = (s < ND) ? base + rank[i]
                                 : base + cntpair[2 * d] + rank[i];
        ssort[pos] = s;
    }
}

// ---------------------------------------------------------------------------
// Fused GAT aggregation + SAGE partial sum over s>=ND neighbors.
// 2 dst per 256-thr block (two independent 128-thr groups; 4 slots x 32
// lanes; lane holds 8 channels). Weight w inline; z folded into gather loop
// (unroll-2). Writes h1a into hcat[:,256:512], psum into hcat[:,0:256].
// ---------------------------------------------------------------------------
__global__ __launch_bounds__(256) void gat_sage(
    const unsigned short* __restrict__ hb, const float* __restrict__ al_s,
    const float* __restrict__ al_d, const int* __restrict__ ssort,
    const int* __restrict__ ptrp, unsigned short* __restrict__ hcat)
{
    __shared__ float ldsg[2][4][264];
    __shared__ float ldss[2][4][264];
    __shared__ float zp[2][4];
    const int tid  = threadIdx.x;
    const int grp  = tid >> 7;
    const int t    = tid & 127;
    const int slot = t >> 5;
    const int l32  = t & 31;
    const int c0   = l32 * 8;
    const int v    = blockIdx.x * 2 + grp;
    const int p0 = ptrp[v], p1 = ptrp[v + 1];

    const float ad     = al_d[v];
    const float w_self = __expf(lrelu02(al_s[v] + ad));

    float accg[8], accs[8];
    float zpart = 0.f;
#pragma unroll
    for (int j = 0; j < 8; ++j) accs[j] = 0.f;
    if (slot == 0) {
        const ushort8v hv = *(const ushort8v*)&hb[(size_t)v * 256 + c0];
#pragma unroll
        for (int j = 0; j < 8; ++j) accg[j] = w_self * us2f(hv[j]);
    } else {
#pragma unroll
        for (int j = 0; j < 8; ++j) accg[j] = 0.f;
    }

    int p = p0 + slot;
    for (; p + 4 < p1; p += 8) {
        const int s0 = ssort[p];
        const int s1 = ssort[p + 4];
        const float w0 = __expf(lrelu02(al_s[s0] + ad));
        const float w1 = __expf(lrelu02(al_s[s1] + ad));
        const ushort8v h0 = *(const ushort8v*)&hb[(size_t)s0 * 256 + c0];
        const ushort8v h1 = *(const ushort8v*)&hb[(size_t)s1 * 256 + c0];
        zpart += w0 + w1;
        const bool g0 = (s0 >= ND), g1 = (s1 >= ND);
#pragma unroll
        for (int j = 0; j < 8; ++j) {
            const float f0 = us2f(h0[j]);
            const float f1 = us2f(h1[j]);
            accg[j] = fmaf(w0, f0, accg[j]);
            accg[j] = fmaf(w1, f1, accg[j]);
            accs[j] += (g0 ? f0 : 0.f) + (g1 ? f1 : 0.f);
        }
    }
    if (p < p1) {
        const int s0 = ssort[p];
        const float w0 = __expf(lrelu02(al_s[s0] + ad));
        const ushort8v h0 = *(const ushort8v*)&hb[(size_t)s0 * 256 + c0];
        zpart += w0;
        const bool g0 = (s0 >= ND);
#pragma unroll
        for (int j = 0; j < 8; ++j) {
            const float f0 = us2f(h0[j]);
            accg[j] = fmaf(w0, f0, accg[j]);
            accs[j] += g0 ? f0 : 0.f;
        }
    }

    if (l32 == 0) zp[grp][slot] = zpart;
    *(f32x4*)&ldsg[grp][slot][c0]     = (f32x4){accg[0], accg[1], accg[2], accg[3]};
    *(f32x4*)&ldsg[grp][slot][c0 + 4] = (f32x4){accg[4], accg[5], accg[6], accg[7]};
    *(f32x4*)&ldss[grp][slot][c0]     = (f32x4){accs[0], accs[1], accs[2], accs[3]};
    *(f32x4*)&ldss[grp][slot][c0 + 4] = (f32x4){accs[4], accs[5], accs[6], accs[7]};
    __syncthreads();

    const float inv_z = 1.0f / (w_self + zp[grp][0] + zp[grp][1] + zp[grp][2] + zp[grp][3]);
    const int c = t * 2;
    float rg0 = 0.f, rg1 = 0.f, rs0 = 0.f, rs1 = 0.f;
#pragma unroll
    for (int s2 = 0; s2 < 4; ++s2) {
        rg0 += ldsg[grp][s2][c];     rg1 += ldsg[grp][s2][c + 1];
        rs0 += ldss[grp][s2][c];     rs1 += ldss[grp][s2][c + 1];
    }
    *(ushort2v*)&hcat[(size_t)v * 512 + 256 + c] =
        (ushort2v){f2us(rg0 * inv_z), f2us(rg1 * inv_z)};
    *(ushort2v*)&hcat[(size_t)v * 512 + c] =
        (ushort2v){f2us(rs0), f2us(rs1)};               // psum (pre-mean)
}

// ---------------------------------------------------------------------------
// SAGE finisher: psum (bf16, in hcat[:,0:256]) += s<ND h1a gathers (class-
// ordered CSR: only first cntpair[2v] edges, no branch); divide by degree.
// ---------------------------------------------------------------------------
__global__ __launch_bounds__(256) void sage_fin(
    const int* __restrict__ ssort, const int* __restrict__ ptrp,
    const int* __restrict__ cntpair, unsigned short* __restrict__ hcat)
{
    const int tid   = threadIdx.x;
    const int g     = tid >> 6;
    const int v     = blockIdx.x * 4 + g;
    const int slot2 = (tid >> 5) & 1;
    const int l32   = tid & 31;
    const int c0    = l32 * 8;
    const int p0  = ptrp[v];
    const int p1l = p0 + cntpair[2 * v];
    const int deg = ptrp[v + 1] - p0;

    float acc[8];
    if (slot2 == 0) {
        const ushort8v pv = *(const ushort8v*)&hcat[(size_t)v * 512 + c0];
#pragma unroll
        for (int j = 0; j < 8; ++j) acc[j] = us2f(pv[j]);
    } else {
#pragma unroll
        for (int j = 0; j < 8; ++j) acc[j] = 0.f;
    }
    int p = p0 + slot2;
    for (; p + 2 < p1l; p += 4) {
        const int s0 = ssort[p];
        const int s1 = ssort[p + 2];
        const ushort8v h0 = *(const ushort8v*)&hcat[(size_t)s0 * 512 + 256 + c0];
        const ushort8v h1 = *(const ushort8v*)&hcat[(size_t)s1 * 512 + 256 + c0];
#pragma unroll
        for (int j = 0; j < 8; ++j) acc[j] += us2f(h0[j]) + us2f(h1[j]);
    }
    if (p < p1l) {
        const int s0 = ssort[p];
        const ushort8v h0 = *(const ushort8v*)&hcat[(size_t)s0 * 512 + 256 + c0];
#pragma unroll
        for (int j = 0; j < 8; ++j) acc[j] += us2f(h0[j]);
    }
#pragma unroll
    for (int j = 0; j < 8; ++j) acc[j] += __shfl_xor(acc[j], 32);

    const float inv = (deg > 0) ? 1.0f / (float)deg : 0.f;
    if (slot2 == 0) {
        ushort8v o;
#pragma unroll
        for (int j = 0; j < 8; ++j) o[j] = f2us(acc[j] * inv);
        *(ushort8v*)&hcat[(size_t)v * 512 + c0] = o;
    }
}

// ---------------------------------------------------------------------------
extern "C" void kernel_launch(void* const* d_in, const int* in_sizes, int n_in,
                              void* d_out, int out_size, void* d_ws, size_t ws_size,
                              hipStream_t stream)
{
    const float* x    = (const float*)d_in[0];
    const float* Wg   = (const float*)d_in[1];
    const float* asrc = (const float*)d_in[2];
    const float* adst = (const float*)d_in[3];
    const float* bg   = (const float*)d_in[4];
    const float* Wl1  = (const float*)d_in[8];
    const float* bl1  = (const float*)d_in[9];
    const float* Wr1  = (const float*)d_in[10];
    const int*   src1 = (const int*)d_in[13];
    const int*   dst1 = (const int*)d_in[14];
    const int E1 = in_sizes[13];

    // workspace (cntpair and done adjacent -> one zero pass)
    char* w = (char*)d_ws;
    unsigned short* hb   = (unsigned short*)w; w += (size_t)NS * 256 * 2;   // 40.96 MB
    unsigned short* hcat = (unsigned short*)w; w += (size_t)ND * 512 * 2;   // 20.48 MB
    unsigned short* Wgp  = (unsigned short*)w; w += 256 * 256 * 2;          // k-panel Wg^T
    unsigned short* Wcp  = (unsigned short*)w; w += 256 * 512 * 2;          // k-panel [Wl;Wr]^T
    float* al_s   = (float*)w; w += (size_t)NS * 4;
    float* al_d   = (float*)w; w += (size_t)NS * 4;
    int* cntpair  = (int*)w;   w += (size_t)2 * ND * 4;
    int* done     = (int*)w;   w += 4 * 4;
    int* ptrv     = (int*)w;   w += (size_t)(ND + 4) * 4;
    int* rank     = (int*)w;   w += (size_t)E1 * 4;
    int* ssort    = (int*)w;   w += (size_t)E1 * 4;

    const dim3 b256(256), b512(512);
    const int nz4 = (2 * ND + 4) / 4;   // cntpair + done in int4s

    prep_misc<<<dim3(512 + (nz4 + 255) / 256), b256, 0, stream>>>(
        Wg, Wl1, Wr1, Wgp, Wcp, cntpair, nz4);

    // h = x @ Wg + bg (bf16) with fused pre-bias al_s/al_d;
    // count_rank fused as tail blocks; scan block spin-waits for them.
    const int nblk0 = NS / 128;
    const int ncnt  = (E1 + 511) / 512;
    gemm_mfma<0, true, true, 256, 128><<<dim3(nblk0 + 1 + ncnt), b512, 0, stream>>>(
        x, Wgp, NS, hb, asrc, adst, al_s, al_d, bg, nullptr,
        nblk0, cntpair, ptrv, src1, dst1, rank, E1, done, ncnt);

    edge_scatter<<<dim3((E1 + 255) / 256), b256, 0, stream>>>(
        src1, dst1, ptrv, rank, cntpair, ssort, E1);

    // fused GAT aggregate + SAGE s>=ND partial sum (psum bf16 in-place)
    gat_sage<<<dim3(ND / 2), b256, 0, stream>>>(hb, al_s, al_d, ssort,
                                                ptrv, hcat);
    // SAGE finisher: s<ND h1a gathers + divide
    sage_fin<<<dim3(ND / 4), b256, 0, stream>>>(ssort, ptrv, cntpair, hcat);

    // out = normalize([mean|h1a] @ [Wl1;Wr1] + bl1); TM=64 -> 313 blocks
    gemm_mfma<1, false, false, 512, 64><<<dim3((ND + 63) / 64), b256, 0, stream>>>(
        hcat, Wcp, ND, nullptr, nullptr, nullptr, nullptr, nullptr,
        bl1, (float*)d_out, 0, nullptr, nullptr, nullptr, nullptr,
        nullptr, 0, nullptr, 0);
}

// Round 18
// 147.013 us; speedup vs baseline: 1.8708x; 1.8708x over previous
//
#include <hip/hip_runtime.h>

// H=256, N1=80000, N2=20000, E1=300000. Layer 0 of the reference is dead code.
// Pipeline: prep (zero cntpair + k-panel weight build) -> count_rank ->
// gemm0 h=x@Wg+bg (bf16 MFMA; scan fused) -> edge_scatter -> gat_sage ->
// sage_fin -> gemm1 (+bias+rownorm).
// R18 = exact revert to R14 (best measured: 146.2us). R17's spin-wait fusion
// regressed to 275us (scan block dispatched before its producer tail blocks
// -> CU-occupying spin + L2 atomic thrash). Plateau candidate: R10/R14/R16
// all 144.5-147.6 (noise band) across every structural GEMM/gather variant.

#define NS 80000
#define ND 20000

typedef float   float4v  __attribute__((ext_vector_type(4)));
typedef float   f32x4    __attribute__((ext_vector_type(4)));
typedef __bf16  bf16x8   __attribute__((ext_vector_type(8)));
typedef unsigned short ushort8v __attribute__((ext_vector_type(8)));
typedef unsigned short ushort2v __attribute__((ext_vector_type(2)));
typedef int     int4v    __attribute__((ext_vector_type(4)));

union frag_u { ushort8v u; bf16x8 b; };

__device__ __forceinline__ float us2f(unsigned short u) {
    union { unsigned int i; float f; } x; x.i = ((unsigned)u) << 16; return x.f;
}
__device__ __forceinline__ unsigned short f2us(float f) {
    union { __bf16 b; unsigned short u; } x; x.b = (__bf16)f; return x.u;
}
__device__ __forceinline__ float lrelu02(float x) { return x > 0.f ? x : 0.2f * x; }

// ---------------------------------------------------------------------------
// prep: blocks 0..255 -> Wgp (k-panel of Wg^T); 256..511 -> Wcp (k-panel of
// [Wl;Wr]^T); 512.. -> zero cntpair.
// k-panel layout: Bp[((k>>3)*256 + col)*8 + (k&7)] = B^T[col][k]
// ---------------------------------------------------------------------------
__global__ __launch_bounds__(256) void prep_misc(
    const float* __restrict__ Wg, const float* __restrict__ Wl,
    const float* __restrict__ Wr, unsigned short* __restrict__ Wgp,
    unsigned short* __restrict__ Wcp, int* __restrict__ zerop, int nz4)
{
    const int b = blockIdx.x, t = threadIdx.x;
    if (b < 256) {
        const int n = b;               // col
        const int k = t;               // 0..255
        Wgp[(((k >> 3) * 256) + n) * 8 + (k & 7)] = f2us(Wg[k * 256 + n]);
    } else if (b < 512) {
        const int n = b - 256;
        const int k0 = t;              // Wl part (k = t)
        const int k1 = t + 256;        // Wr part
        Wcp[(((k0 >> 3) * 256) + n) * 8 + (k0 & 7)] = f2us(Wl[t * 256 + n]);
        Wcp[(((k1 >> 3) * 256) + n) * 8 + (k1 & 7)] = f2us(Wr[t * 256 + n]);
    } else {
        const int i = (b - 512) * 256 + t;
        if (i < nz4) ((int4v*)zerop)[i] = (int4v){0, 0, 0, 0};
    }
}

// ---------------------------------------------------------------------------
// count + rank within class
// ---------------------------------------------------------------------------
__global__ void count_rank(const int* __restrict__ src, const int* __restrict__ dst,
                           int* __restrict__ cntpair, int* __restrict__ rank, int E)
{
    const int i = blockIdx.x * 256 + threadIdx.x;
    if (i < E) {
        const int d = dst[i];
        const int cls = (src[i] < ND) ? 0 : 1;
        rank[i] = atomicAdd(&cntpair[2 * d + cls], 1);
    }
}

// ---------------------------------------------------------------------------
// bf16 MFMA GEMM: C[M,256] = A[M,KC] @ Bp (k-panel of B^T)
// 512 thr = 8 waves (2 row x 4 col); tile 128x256; BK=32; KC templated.
// A-only dbuf LDS (20KB); B frags DIRECT from global k-panel (coalesced);
// 1 barrier per K-step; A(kt+1) issued at top.
// ---------------------------------------------------------------------------
template <int EPI, bool AF32, bool SCAN, int KC>
__global__ __launch_bounds__(512) void gemm_mfma(
    const void* __restrict__ Av, const unsigned short* __restrict__ Bp,
    int M,
    unsigned short* __restrict__ hb_out,
    const float* __restrict__ avs, const float* __restrict__ avd,
    float* __restrict__ al_s, float* __restrict__ al_d,
    const float* __restrict__ bias, float* __restrict__ outp,
    int nblk, const int* __restrict__ cntpair, int* __restrict__ ptrp)
{
    __shared__ __align__(16) unsigned short Als[2][128][40];
    __shared__ float red0[128];
    __shared__ float red1[128];
    __shared__ int   part[512];

    if (SCAN && (int)blockIdx.x >= nblk) {
        const int tid = threadIdx.x;
        const int chunk = (ND + 511) / 512;
        const int i0 = tid * chunk;
        const int i1 = min(i0 + chunk, ND);
        int s = 0;
        for (int i = i0; i < i1; ++i) s += cntpair[2*i] + cntpair[2*i+1];
        part[tid] = s;
        __syncthreads();
        for (int off = 1; off < 512; off <<= 1) {
            const int t = (tid >= off) ? part[tid - off] : 0;
            __syncthreads();
            part[tid] += t;
            __syncthreads();
        }
        int run = tid ? part[tid - 1] : 0;
        for (int i = i0; i < i1; ++i) { ptrp[i] = run; run += cntpair[2*i] + cntpair[2*i+1]; }
        if (tid == 511) ptrp[ND] = part[511];
        return;
    }

    const int tid  = threadIdx.x;
    const int lane = tid & 63;
    const int wid  = tid >> 6;
    const int wr   = wid >> 2;      // 0..1 : 64-row half
    const int wc   = wid & 3;       // 0..3 : 64-col quarter
    const int row0 = blockIdx.x * 128;
    const int lg   = lane >> 4;     // 0..3
    const int lm   = lane & 15;

    f32x4 acc[4][4] = {};
    constexpr int nk = KC >> 5;

    const int arow = tid >> 2;
    const int akof = (tid & 3) * 8;

    float4v ar0, ar1;
    ushort8v ai;

    auto loadA = [&](int kt) {
        const int k0 = kt * 32 + akof;
        const int grow = row0 + arow;
        if constexpr (AF32) {
            const float* p = (const float*)Av + (size_t)grow * KC + k0;
            ar0 = *(const float4v*)p;
            ar1 = *(const float4v*)(p + 4);
        } else {
            if (grow < M)
                ai = *(const ushort8v*)((const unsigned short*)Av + (size_t)grow * KC + k0);
            else
                ai = (ushort8v){0,0,0,0,0,0,0,0};
        }
    };
    auto storeA = [&](int b) {
        if constexpr (AF32) {
            ushort8v t;
            t[0] = f2us(ar0[0]); t[1] = f2us(ar0[1]); t[2] = f2us(ar0[2]); t[3] = f2us(ar0[3]);
            t[4] = f2us(ar1[0]); t[5] = f2us(ar1[1]); t[6] = f2us(ar1[2]); t[7] = f2us(ar1[3]);
            *(ushort8v*)&Als[b][arow][akof] = t;
        } else {
            *(ushort8v*)&Als[b][arow][akof] = ai;
        }
    };

    loadA(0); storeA(0); __syncthreads();
    int cur = 0;

#pragma unroll
    for (int kt = 0; kt < nk; ++kt) {
        if (kt + 1 < nk) loadA(kt + 1);
        frag_u bf[4];
#pragma unroll
        for (int n = 0; n < 4; ++n)
            bf[n].u = *(const ushort8v*)(Bp +
                ((size_t)(kt*4 + lg) * 256 + wc*64 + n*16 + lm) * 8);
        frag_u af[4];
#pragma unroll
        for (int m = 0; m < 4; ++m)
            af[m].u = *(const ushort8v*)&Als[cur][wr*64 + m*16 + lm][lg*8];
#pragma unroll
        for (int m = 0; m < 4; ++m)
#pragma unroll
            for (int n = 0; n < 4; ++n)
                acc[m][n] = __builtin_amdgcn_mfma_f32_16x16x32_bf16(
                    af[m].b, bf[n].b, acc[m][n], 0, 0, 0);
        if (kt + 1 < nk) {
            storeA(cur ^ 1);
            __syncthreads();
            cur ^= 1;
        }
    }

    if constexpr (EPI == 0) {
        if (tid < 128) { red0[tid] = 0.f; red1[tid] = 0.f; }
        __syncthreads();
        float asv[4], adv[4], bgv[4];
#pragma unroll
        for (int n = 0; n < 4; ++n) {
            const int col = wc*64 + n*16 + lm;
            asv[n] = avs[col]; adv[n] = avd[col]; bgv[n] = bias[col];
        }
#pragma unroll
        for (int m = 0; m < 4; ++m) {
#pragma unroll
            for (int j = 0; j < 4; ++j) {
                const int lr = wr*64 + m*16 + lg*4 + j;
                float ps = 0.f, pd = 0.f;
#pragma unroll
                for (int n = 0; n < 4; ++n) {
                    const float v = acc[m][n][j];
                    ps += v * asv[n]; pd += v * adv[n];
                    hb_out[(size_t)(row0 + lr) * 256 + wc*64 + n*16 + lm] = f2us(v + bgv[n]);
                }
#pragma unroll
                for (int off = 1; off < 16; off <<= 1) {
                    ps += __shfl_xor(ps, off);
                    pd += __shfl_xor(pd, off);
                }
                if (lm == 0) { atomicAdd(&red0[lr], ps); atomicAdd(&red1[lr], pd); }
            }
        }
        __syncthreads();
        if (tid < 128) { al_s[row0 + tid] = red0[tid]; al_d[row0 + tid] = red1[tid]; }
    } else {
        if (tid < 128) red0[tid] = 0.f;
        __syncthreads();
        float bv[4];
#pragma unroll
        for (int n = 0; n < 4; ++n) bv[n] = bias[wc*64 + n*16 + lm];
#pragma unroll
        for (int m = 0; m < 4; ++m) {
#pragma unroll
            for (int j = 0; j < 4; ++j) {
                const int lr = wr*64 + m*16 + lg*4 + j;
                float ss = 0.f;
#pragma unroll
                for (int n = 0; n < 4; ++n) {
                    const float v = acc[m][n][j] + bv[n];
                    acc[m][n][j] = v;
                    ss += v * v;
                }
#pragma unroll
                for (int off = 1; off < 16; off <<= 1) ss += __shfl_xor(ss, off);
                if (lm == 0) atomicAdd(&red0[lr], ss);
            }
        }
        __syncthreads();
#pragma unroll
        for (int m = 0; m < 4; ++m) {
#pragma unroll
            for (int j = 0; j < 4; ++j) {
                const int lr = wr*64 + m*16 + lg*4 + j;
                const int grow = row0 + lr;
                if (grow < M) {
                    const float inv = 1.0f / fmaxf(sqrtf(red0[lr]), 1e-12f);
#pragma unroll
                    for (int n = 0; n < 4; ++n)
                        outp[(size_t)grow * 256 + wc*64 + n*16 + lm] = acc[m][n][j] * inv;
                }
            }
        }
    }
}

// ---------------------------------------------------------------------------
// scatter: atomic-free via rank; class-ordered (s<ND first within each row)
// ---------------------------------------------------------------------------
__global__ void edge_scatter(const int* __restrict__ src, const int* __restrict__ dst,
                             const int* __restrict__ ptrp, const int* __restrict__ rank,
                             const int* __restrict__ cntpair,
                             int* __restrict__ ssort, int E)
{
    const int i = blockIdx.x * 256 + threadIdx.x;
    if (i < E) {
        const int d = dst[i];
        const int s = src[i];
        const int base = ptrp[d];
        const int pos = (s < ND) ? base + rank[i]
                                 : base + cntpair[2 * d] + rank[i];
        ssort[pos] = s;
    }
}

// ---------------------------------------------------------------------------
// Fused GAT aggregation + SAGE partial sum over s>=ND neighbors.
// Block=128: 4 slots x 32 lanes; lane holds 8 channels. Weight w computed
// inline (al_s L2-resident broadcast). z folded into gather loop; unroll-2.
// Writes h1a into hcat[:,256:512] and s>=ND partial sum into hcat[:,0:256].
// ---------------------------------------------------------------------------
__global__ __launch_bounds__(128) void gat_sage(
    const unsigned short* __restrict__ hb, const float* __restrict__ al_s,
    const float* __restrict__ al_d, const int* __restrict__ ssort,
    const int* __restrict__ ptrp, unsigned short* __restrict__ hcat)
{
    __shared__ float ldsg[4][264];
    __shared__ float ldss[4][264];
    __shared__ float zp[4];
    const int v    = blockIdx.x;
    const int tid  = threadIdx.x;
    const int slot = tid >> 5;      // 0..3
    const int l32  = tid & 31;
    const int c0   = l32 * 8;
    const int p0 = ptrp[v], p1 = ptrp[v + 1];

    const float ad     = al_d[v];
    const float w_self = __expf(lrelu02(al_s[v] + ad));

    float accg[8], accs[8];
    float zpart = 0.f;
#pragma unroll
    for (int j = 0; j < 8; ++j) accs[j] = 0.f;
    if (slot == 0) {
        const ushort8v hv = *(const ushort8v*)&hb[(size_t)v * 256 + c0];
#pragma unroll
        for (int j = 0; j < 8; ++j) accg[j] = w_self * us2f(hv[j]);
    } else {
#pragma unroll
        for (int j = 0; j < 8; ++j) accg[j] = 0.f;
    }

    int p = p0 + slot;
    for (; p + 4 < p1; p += 8) {            // 2 edges per iteration
        const int s0 = ssort[p];
        const int s1 = ssort[p + 4];
        const float w0 = __expf(lrelu02(al_s[s0] + ad));
        const float w1 = __expf(lrelu02(al_s[s1] + ad));
        const ushort8v h0 = *(const ushort8v*)&hb[(size_t)s0 * 256 + c0];
        const ushort8v h1 = *(const ushort8v*)&hb[(size_t)s1 * 256 + c0];
        zpart += w0 + w1;
        const bool g0 = (s0 >= ND), g1 = (s1 >= ND);
#pragma unroll
        for (int j = 0; j < 8; ++j) {
            const float f0 = us2f(h0[j]);
            const float f1 = us2f(h1[j]);
            accg[j] = fmaf(w0, f0, accg[j]);
            accg[j] = fmaf(w1, f1, accg[j]);
            accs[j] += (g0 ? f0 : 0.f) + (g1 ? f1 : 0.f);
        }
    }
    if (p < p1) {                           // tail edge
        const int s0 = ssort[p];
        const float w0 = __expf(lrelu02(al_s[s0] + ad));
        const ushort8v h0 = *(const ushort8v*)&hb[(size_t)s0 * 256 + c0];
        zpart += w0;
        const bool g0 = (s0 >= ND);
#pragma unroll
        for (int j = 0; j < 8; ++j) {
            const float f0 = us2f(h0[j]);
            accg[j] = fmaf(w0, f0, accg[j]);
            accs[j] += g0 ? f0 : 0.f;
        }
    }

    if (l32 == 0) zp[slot] = zpart;
    *(f32x4*)&ldsg[slot][c0]     = (f32x4){accg[0], accg[1], accg[2], accg[3]};
    *(f32x4*)&ldsg[slot][c0 + 4] = (f32x4){accg[4], accg[5], accg[6], accg[7]};
    *(f32x4*)&ldss[slot][c0]     = (f32x4){accs[0], accs[1], accs[2], accs[3]};
    *(f32x4*)&ldss[slot][c0 + 4] = (f32x4){accs[4], accs[5], accs[6], accs[7]};
    __syncthreads();

    const float inv_z = 1.0f / (w_self + zp[0] + zp[1] + zp[2] + zp[3]);
    const int c = tid * 2;          // 2 channels per thread
    float rg0 = 0.f, rg1 = 0.f, rs0 = 0.f, rs1 = 0.f;
#pragma unroll
    for (int s2 = 0; s2 < 4; ++s2) {
        rg0 += ldsg[s2][c];     rg1 += ldsg[s2][c + 1];
        rs0 += ldss[s2][c];     rs1 += ldss[s2][c + 1];
    }
    *(ushort2v*)&hcat[(size_t)v * 512 + 256 + c] =
        (ushort2v){f2us(rg0 * inv_z), f2us(rg1 * inv_z)};
    *(ushort2v*)&hcat[(size_t)v * 512 + c] =
        (ushort2v){f2us(rs0), f2us(rs1)};               // psum (pre-mean)
}

// ---------------------------------------------------------------------------
// SAGE finisher: psum (bf16, in hcat[:,0:256]) += s<ND h1a gathers (class-
// ordered CSR: only first cntpair[2v] edges, no branch); divide by degree.
// ---------------------------------------------------------------------------
__global__ __launch_bounds__(256) void sage_fin(
    const int* __restrict__ ssort, const int* __restrict__ ptrp,
    const int* __restrict__ cntpair, unsigned short* __restrict__ hcat)
{
    const int tid   = threadIdx.x;
    const int g     = tid >> 6;                 // 0..3 (one wave per dst)
    const int v     = blockIdx.x * 4 + g;
    const int slot2 = (tid >> 5) & 1;
    const int l32   = tid & 31;
    const int c0    = l32 * 8;
    const int p0  = ptrp[v];
    const int p1l = p0 + cntpair[2 * v];        // lt-edges only
    const int deg = ptrp[v + 1] - p0;

    float acc[8];
    if (slot2 == 0) {
        const ushort8v pv = *(const ushort8v*)&hcat[(size_t)v * 512 + c0];
#pragma unroll
        for (int j = 0; j < 8; ++j) acc[j] = us2f(pv[j]);
    } else {
#pragma unroll
        for (int j = 0; j < 8; ++j) acc[j] = 0.f;
    }
    int p = p0 + slot2;
    for (; p + 2 < p1l; p += 4) {               // 2 edges per iteration
        const int s0 = ssort[p];
        const int s1 = ssort[p + 2];
        const ushort8v h0 = *(const ushort8v*)&hcat[(size_t)s0 * 512 + 256 + c0];
        const ushort8v h1 = *(const ushort8v*)&hcat[(size_t)s1 * 512 + 256 + c0];
#pragma unroll
        for (int j = 0; j < 8; ++j) acc[j] += us2f(h0[j]) + us2f(h1[j]);
    }
    if (p < p1l) {
        const int s0 = ssort[p];
        const ushort8v h0 = *(const ushort8v*)&hcat[(size_t)s0 * 512 + 256 + c0];
#pragma unroll
        for (int j = 0; j < 8; ++j) acc[j] += us2f(h0[j]);
    }
#pragma unroll
    for (int j = 0; j < 8; ++j) acc[j] += __shfl_xor(acc[j], 32);

    const float inv = (deg > 0) ? 1.0f / (float)deg : 0.f;
    if (slot2 == 0) {
        ushort8v o;
#pragma unroll
        for (int j = 0; j < 8; ++j) o[j] = f2us(acc[j] * inv);
        *(ushort8v*)&hcat[(size_t)v * 512 + c0] = o;
    }
}

// ---------------------------------------------------------------------------
extern "C" void kernel_launch(void* const* d_in, const int* in_sizes, int n_in,
                              void* d_out, int out_size, void* d_ws, size_t ws_size,
                              hipStream_t stream)
{
    const float* x    = (const float*)d_in[0];
    const float* Wg   = (const float*)d_in[1];
    const float* asrc = (const float*)d_in[2];
    const float* adst = (const float*)d_in[3];
    const float* bg   = (const float*)d_in[4];
    const float* Wl1  = (const float*)d_in[8];
    const float* bl1  = (const float*)d_in[9];
    const float* Wr1  = (const float*)d_in[10];
    const int*   src1 = (const int*)d_in[13];
    const int*   dst1 = (const int*)d_in[14];
    const int E1 = in_sizes[13];

    // workspace
    char* w = (char*)d_ws;
    unsigned short* hb   = (unsigned short*)w; w += (size_t)NS * 256 * 2;   // 40.96 MB
    unsigned short* hcat = (unsigned short*)w; w += (size_t)ND * 512 * 2;   // 20.48 MB
    unsigned short* Wgp  = (unsigned short*)w; w += 256 * 256 * 2;          // k-panel Wg^T
    unsigned short* Wcp  = (unsigned short*)w; w += 256 * 512 * 2;          // k-panel [Wl;Wr]^T
    float* al_s   = (float*)w; w += (size_t)NS * 4;
    float* al_d   = (float*)w; w += (size_t)NS * 4;
    int* cntpair  = (int*)w;   w += (size_t)2 * ND * 4;
    int* ptrv     = (int*)w;   w += (size_t)(ND + 4) * 4;
    int* rank     = (int*)w;   w += (size_t)E1 * 4;
    int* ssort    = (int*)w;   w += (size_t)E1 * 4;

    const dim3 b256(256), b512(512);
    const int nz4 = 2 * ND / 4;   // cntpair in int4s

    prep_misc<<<dim3(512 + (nz4 + 255) / 256), b256, 0, stream>>>(
        Wg, Wl1, Wr1, Wgp, Wcp, cntpair, nz4);

    count_rank<<<dim3((E1 + 255) / 256), b256, 0, stream>>>(
        src1, dst1, cntpair, rank, E1);

    // h = x @ Wg + bg (bf16) with fused pre-bias al_s/al_d; scan fused
    const int nblk0 = NS / 128;
    gemm_mfma<0, true, true, 256><<<dim3(nblk0 + 1), b512, 0, stream>>>(
        x, Wgp, NS, hb, asrc, adst, al_s, al_d, bg, nullptr,
        nblk0, cntpair, ptrv);

    edge_scatter<<<dim3((E1 + 255) / 256), b256, 0, stream>>>(
        src1, dst1, ptrv, rank, cntpair, ssort, E1);

    // fused GAT aggregate + SAGE s>=ND partial sum (psum bf16 in-place)
    gat_sage<<<dim3(ND), dim3(128), 0, stream>>>(hb, al_s, al_d, ssort,
                                                 ptrv, hcat);
    // SAGE finisher: s<ND h1a gathers + divide
    sage_fin<<<dim3(ND / 4), b256, 0, stream>>>(ssort, ptrv, cntpair, hcat);

    // out = normalize([mean|h1a] @ [Wl1;Wr1] + bl1)
    gemm_mfma<1, false, false, 512><<<dim3((ND + 127) / 128), b512, 0, stream>>>(
        hcat, Wcp, ND, nullptr, nullptr, nullptr, nullptr, nullptr,
        bl1, (float*)d_out, 0, nullptr, nullptr);
}